// Round 6
// baseline (89.206 us; speedup 1.0000x reference)
//
#include <hip/hip_runtime.h>

#define B_ 4
#define N_ 2048
#define IND_ 128
#define H_ 4
#define D_ 64
#define HD_ 256
#define LEAKY 0.2f
#define BNEPS 1e-5f
#define LOG2E 1.44269504088896340736f

typedef float f32x4 __attribute__((ext_vector_type(4)));
typedef short s16x8 __attribute__((ext_vector_type(8)));
typedef unsigned int u32x4 __attribute__((ext_vector_type(4)));

static __device__ __forceinline__ unsigned short f2bf(float f) {
  unsigned u = __builtin_bit_cast(unsigned, f);
  u = (u + 0x7fffu + ((u >> 16) & 1u)) >> 16;   // RNE
  return (unsigned short)u;
}
static __device__ __forceinline__ unsigned encf(float f) {
  unsigned u = __builtin_bit_cast(unsigned, f);
  return (u & 0x80000000u) ? ~u : (u | 0x80000000u);
}
static __device__ __forceinline__ float decf(unsigned u) {
  unsigned b = (u & 0x80000000u) ? (u ^ 0x80000000u) : ~u;
  return __builtin_bit_cast(float, b);
}

// ---------------- Kernel A: pack adjacency + zero accumulators ------------
__global__ __launch_bounds__(256) void k_pack_adj(const int* __restrict__ adj,
                                                  unsigned* __restrict__ bits,
                                                  float* __restrict__ zbuf) {
  if (blockIdx.x == 0) {
    for (int i = threadIdx.x; i < 576; i += 256) zbuf[i] = 0.f;
  }
  int idx = blockIdx.x * 256 + threadIdx.x;     // flat over N*N (row-major)
  int val = adj[idx] != 0;
  unsigned long long m = __ballot(val);
  int lane = threadIdx.x & 63;
  if (lane == 0)       bits[idx >> 5] = (unsigned)m;
  else if (lane == 32) bits[idx >> 5] = (unsigned)(m >> 32);
}

// ---------------- Kernel B: Wh = h @ W (bf16, transposed) + src/dst -------
__global__ __launch_bounds__(256) void k_gemm(const float* __restrict__ h,
                                              const float* __restrict__ W,
                                              const float* __restrict__ a,
                                              unsigned short* __restrict__ wht,
                                              float* __restrict__ src,
                                              float* __restrict__ dst,
                                              unsigned* __restrict__ dmaxU) {
  __shared__ float hl[16 * 128];     // 8 KB
  __shared__ float tr[256 * 17];     // 17 KB transpose buffer
  int t = threadIdx.x;
  int rowbase = blockIdx.x * 16;               // global row m in [0, B*N)
  const f32x4* hg = (const f32x4*)(h + (size_t)rowbase * 128);
  f32x4* hl4 = (f32x4*)hl;
  hl4[t] = hg[t];
  hl4[t + 256] = hg[t + 256];
  __syncthreads();

  int lane = t & 63, q = t >> 6;               // wave q owns rows q*4..q*4+3
  float acc[4][4];
#pragma unroll
  for (int rr = 0; rr < 4; rr++)
#pragma unroll
    for (int cc = 0; cc < 4; cc++) acc[rr][cc] = 0.f;

#pragma unroll 2
  for (int k4 = 0; k4 < 32; k4++) {
    f32x4 hv[4], wv[4];
#pragma unroll
    for (int rr = 0; rr < 4; rr++)
      hv[rr] = *(const f32x4*)&hl[(q * 4 + rr) * 128 + k4 * 4];
#pragma unroll
    for (int kk = 0; kk < 4; kk++)
      wv[kk] = *(const f32x4*)(W + (size_t)(k4 * 4 + kk) * 256 + lane * 4);
#pragma unroll
    for (int kk = 0; kk < 4; kk++)
#pragma unroll
      for (int rr = 0; rr < 4; rr++)
#pragma unroll
        for (int cc = 0; cc < 4; cc++)
          acc[rr][cc] = fmaf(hv[rr][kk], wv[kk][cc], acc[rr][cc]);
  }

  // ---- fused src/dst: thread's 4 channels (lane*4..) share hh = lane>>4
  int b = rowbase >> 11, n0 = rowbase & 2047;
  {
    int hh = lane >> 4;
    int dbase = (lane & 15) * 4;
    float aS[4], aD[4];
#pragma unroll
    for (int cc = 0; cc < 4; cc++) {
      aS[cc] = a[hh * 128 + dbase + cc] * LOG2E;
      aD[cc] = a[hh * 128 + 64 + dbase + cc] * LOG2E;
    }
    float dmx = -1e30f;
#pragma unroll
    for (int rr = 0; rr < 4; rr++) {
      float sv = 0.f, dv = 0.f;
#pragma unroll
      for (int cc = 0; cc < 4; cc++) {
        sv = fmaf(acc[rr][cc], aS[cc], sv);
        dv = fmaf(acc[rr][cc], aD[cc], dv);
      }
#pragma unroll
      for (int off = 1; off < 16; off <<= 1) {
        sv += __shfl_xor(sv, off);
        dv += __shfl_xor(dv, off);
      }
      if ((lane & 15) == 0) {
        int n = n0 + q * 4 + rr;
        src[(size_t)(b * 4 + hh) * 2048 + n] = sv;
        dst[(size_t)(b * 4 + hh) * 2048 + n] = dv;
        dmx = fmaxf(dmx, dv);
      }
    }
    if ((lane & 15) == 0) atomicMax(&dmaxU[b * 4 + hh], encf(dmx));
  }

  // ---- transpose through LDS (pad 17), emit bf16 wht
#pragma unroll
  for (int rr = 0; rr < 4; rr++)
#pragma unroll
    for (int cc = 0; cc < 4; cc++)
      tr[(lane * 4 + cc) * 17 + q * 4 + rr] = acc[rr][cc];
  __syncthreads();

  int c = t;                 // output channel 0..255
  int d = c & 63, hh = c >> 6;
  u32x4 wv2[2];
#pragma unroll
  for (int i = 0; i < 2; i++) {
#pragma unroll
    for (int jj = 0; jj < 4; jj++) {
      unsigned lo = f2bf(tr[c * 17 + (i * 4 + jj) * 2]);
      unsigned hi = f2bf(tr[c * 17 + (i * 4 + jj) * 2 + 1]);
      wv2[i][jj] = lo | (hi << 16);
    }
  }
  u32x4* outp = (u32x4*)(wht + ((size_t)((b * H_ + hh) * 64 + d)) * 2048 + n0);
  outp[0] = wv2[0];
  outp[1] = wv2[1];
}

// ---------------- Kernel C: barrier-free flash attention ------------------
// 256 thr / 32 i-rows / grid 1024. Wave w owns j-quarter w and all 32 rows
// (2 A-frags). B-frags read DIRECTLY from L2 (no LDS staging, no barriers
// in main loop). u/v/adj in LDS, read-only after init. Quarter partials
// combined through LDS at the end.
__global__ __launch_bounds__(256, 4) void k_attn(const unsigned* __restrict__ adjb,
                                                 const unsigned short* __restrict__ wht,
                                                 const float* __restrict__ src,
                                                 const float* __restrict__ dst,
                                                 const unsigned* __restrict__ dmaxU,
                                                 float* __restrict__ hnew,
                                                 float* __restrict__ chsum,
                                                 float* __restrict__ chsq) {
  __shared__ char smem[8704 + 16384];     // adj[32][68] | ul[2048] | vl[2048]
  unsigned* adj_s = (unsigned*)smem;
  float* ul = (float*)(smem + 8704);
  float* vl = ul + 2048;

  int t = threadIdx.x;
  int bid = blockIdx.x;
  int bh = bid & 15, it = bid >> 4;       // 16 consecutive blocks share adj tile
  int b = bh >> 2, hh = bh & 3;
  int i0 = it * 32;
  int q = t >> 6, lane = t & 63, m = lane & 15, g = lane >> 4;

  {   // stage adj rows [i0, i0+32): 32 x 64 words, stride 68 (16B-aligned)
    int r = t >> 3, w8 = (t & 7) * 8;
    const u32x4* gp = (const u32x4*)(adjb + (size_t)(i0 + r) * 64 + w8);
    u32x4 a0 = gp[0], a1 = gp[1];
    *(u32x4*)&adj_s[r * 68 + w8] = a0;
    *(u32x4*)&adj_s[r * 68 + w8 + 4] = a1;
  }
  {   // u_j = 2^dstL_j, v_j = 2^(0.2 dstL_j) for all 2048 j
    const f32x4* dg = (const f32x4*)(dst + (size_t)bh * 2048);
    f32x4 d0 = dg[2 * t], d1 = dg[2 * t + 1];
    f32x4 u0, u1, v0, v1;
#pragma unroll
    for (int e = 0; e < 4; e++) {
      u0[e] = __builtin_amdgcn_exp2f(d0[e]);
      v0[e] = __builtin_amdgcn_exp2f(0.2f * d0[e]);
      u1[e] = __builtin_amdgcn_exp2f(d1[e]);
      v1[e] = __builtin_amdgcn_exp2f(0.2f * d1[e]);
    }
    ((f32x4*)ul)[2 * t] = u0;  ((f32x4*)ul)[2 * t + 1] = u1;
    ((f32x4*)vl)[2 * t] = v0;  ((f32x4*)vl)[2 * t + 1] = v1;
  }

  float dmaxL = decf(dmaxU[bh]);
  float srcL0 = src[(size_t)bh * 2048 + i0 + m];        // frag 0: row i0+m
  float srcL1 = src[(size_t)bh * 2048 + i0 + 16 + m];   // frag 1: row i0+16+m
  float sM0 = srcL0 + dmaxL, sM1 = srcL1 + dmaxL;
  float nM0 = -fmaxf(sM0, LEAKY * sM0), nM1 = -fmaxf(sM1, LEAKY * sM1);
  float Af0 = __builtin_amdgcn_exp2f(srcL0 + nM0);
  float Bf0 = __builtin_amdgcn_exp2f(fmaf(LEAKY, srcL0, nM0));
  float Af1 = __builtin_amdgcn_exp2f(srcL1 + nM1);
  float Bf1 = __builtin_amdgcn_exp2f(fmaf(LEAKY, srcL1, nM1));

  s16x8 bones;
#pragma unroll
  for (int e = 0; e < 8; e++) bones[e] = (short)0x3F80;   // bf16 1.0

  f32x4 acc0[4], acc1[4], den0, den1;
#pragma unroll
  for (int db = 0; db < 4; db++) {
    acc0[db] = (f32x4){0.f, 0.f, 0.f, 0.f};
    acc1[db] = (f32x4){0.f, 0.f, 0.f, 0.f};
  }
  den0 = (f32x4){0.f, 0.f, 0.f, 0.f};
  den1 = (f32x4){0.f, 0.f, 0.f, 0.f};

  const unsigned short* wp[4];
#pragma unroll
  for (int db = 0; db < 4; db++)
    wp[db] = wht + (size_t)(bh * 64 + db * 16 + m) * 2048 + g * 8;

  __syncthreads();      // adj/ul/vl ready; last barrier before main loop

  int jq = q * 512;
  s16x8 bfn[4];
#pragma unroll
  for (int db = 0; db < 4; db++) bfn[db] = *(const s16x8*)(wp[db] + jq);

#pragma unroll 2
  for (int st = 0; st < 16; st++) {
    int j0 = jq + st * 32;
    s16x8 bfc[4];
#pragma unroll
    for (int db = 0; db < 4; db++) bfc[db] = bfn[db];
    if (st < 15) {
#pragma unroll
      for (int db = 0; db < 4; db++)
        bfn[db] = *(const s16x8*)(wp[db] + j0 + 32);
    }

    int widx = j0 >> 5;
    unsigned bits0 = (adj_s[m * 68 + widx] >> (g * 8)) & 0xffu;
    unsigned bits1 = (adj_s[(16 + m) * 68 + widx] >> (g * 8)) & 0xffu;
    const float* up = &ul[j0 + g * 8];
    const float* vp = &vl[j0 + g * 8];
    f32x4 u0 = *(const f32x4*)up, u1 = *(const f32x4*)(up + 4);
    f32x4 v0 = *(const f32x4*)vp, v1 = *(const f32x4*)(vp + 4);

    u32x4 af0u, af1u;
#pragma unroll
    for (int e2 = 0; e2 < 4; e2++) {
      float ua = (e2 < 2) ? u0[2 * e2] : u1[2 * e2 - 4];
      float ub = (e2 < 2) ? u0[2 * e2 + 1] : u1[2 * e2 - 3];
      float va = (e2 < 2) ? v0[2 * e2] : v1[2 * e2 - 4];
      float vb = (e2 < 2) ? v0[2 * e2 + 1] : v1[2 * e2 - 3];
      // frag 0
      float pa = fmaxf(Af0 * ua, Bf0 * va);
      float pb = fmaxf(Af0 * ub, Bf0 * vb);
      unsigned ka = (unsigned)(((int)(bits0 << (31 - 2 * e2))) >> 31);
      unsigned kb = (unsigned)(((int)(bits0 << (30 - 2 * e2))) >> 31);
      pa = __builtin_bit_cast(float, __builtin_bit_cast(unsigned, pa) & ka);
      pb = __builtin_bit_cast(float, __builtin_bit_cast(unsigned, pb) & kb);
      unsigned rr_;
      asm("v_cvt_pk_bf16_f32 %0, %1, %2" : "=v"(rr_) : "v"(pa), "v"(pb));
      af0u[e2] = rr_;
      // frag 1
      float pc = fmaxf(Af1 * ua, Bf1 * va);
      float pd = fmaxf(Af1 * ub, Bf1 * vb);
      unsigned kc = (unsigned)(((int)(bits1 << (31 - 2 * e2))) >> 31);
      unsigned kd = (unsigned)(((int)(bits1 << (30 - 2 * e2))) >> 31);
      pc = __builtin_bit_cast(float, __builtin_bit_cast(unsigned, pc) & kc);
      pd = __builtin_bit_cast(float, __builtin_bit_cast(unsigned, pd) & kd);
      unsigned rr2_;
      asm("v_cvt_pk_bf16_f32 %0, %1, %2" : "=v"(rr2_) : "v"(pc), "v"(pd));
      af1u[e2] = rr2_;
    }
    s16x8 af0 = __builtin_bit_cast(s16x8, af0u);
    s16x8 af1 = __builtin_bit_cast(s16x8, af1u);

#pragma unroll
    for (int db = 0; db < 4; db++)
      acc0[db] = __builtin_amdgcn_mfma_f32_16x16x32_bf16(af0, bfc[db], acc0[db], 0, 0, 0);
    den0 = __builtin_amdgcn_mfma_f32_16x16x32_bf16(af0, bones, den0, 0, 0, 0);
#pragma unroll
    for (int db = 0; db < 4; db++)
      acc1[db] = __builtin_amdgcn_mfma_f32_16x16x32_bf16(af1, bfc[db], acc1[db], 0, 0, 0);
    den1 = __builtin_amdgcn_mfma_f32_16x16x32_bf16(af1, bones, den1, 0, 0, 0);
  }

  // ---- combine quarter partials through LDS (adj/ul/vl now dead) --------
  float* bufA = (float*)smem;             // [32][68], col 64 = den
  float* bufB = (float*)(smem + 8704);
  __syncthreads();

#define WRPART(buf_) { \
    _Pragma("unroll") for (int db = 0; db < 4; db++) \
      _Pragma("unroll") for (int r = 0; r < 4; r++) { \
        (buf_)[(4 * g + r) * 68 + db * 16 + m] = acc0[db][r]; \
        (buf_)[(16 + 4 * g + r) * 68 + db * 16 + m] = acc1[db][r]; } \
    if (m == 0) { \
      _Pragma("unroll") for (int r = 0; r < 4; r++) { \
        (buf_)[(4 * g + r) * 68 + 64] = den0[r]; \
        (buf_)[(16 + 4 * g + r) * 68 + 64] = den1[r]; } } }

#define ADDPART(buf_) { \
    _Pragma("unroll") for (int db = 0; db < 4; db++) \
      _Pragma("unroll") for (int r = 0; r < 4; r++) { \
        acc0[db][r] += (buf_)[(4 * g + r) * 68 + db * 16 + m]; \
        acc1[db][r] += (buf_)[(16 + 4 * g + r) * 68 + db * 16 + m]; } \
    _Pragma("unroll") for (int r = 0; r < 4; r++) { \
      den0[r] += (buf_)[(4 * g + r) * 68 + 64]; \
      den1[r] += (buf_)[(16 + 4 * g + r) * 68 + 64]; } }

  if (q == 1) WRPART(bufA);
  if (q == 3) WRPART(bufB);
  __syncthreads();
  if (q == 0) ADDPART(bufA);
  if (q == 2) ADDPART(bufB);
  __syncthreads();
  if (q == 2) WRPART(bufA);
  __syncthreads();

  if (q == 0) {
    ADDPART(bufA);
    float sums[4] = {0.f, 0.f, 0.f, 0.f}, sqs[4] = {0.f, 0.f, 0.f, 0.f};
#pragma unroll
    for (int fr = 0; fr < 2; fr++) {
#pragma unroll
      for (int r = 0; r < 4; r++) {
        float dt = fr ? den1[r] : den0[r];
        float inv = dt > 0.f ? 1.0f / dt : 0.f;   // all-masked row -> zeros
        int n = i0 + fr * 16 + 4 * g + r;
#pragma unroll
        for (int db = 0; db < 4; db++) {
          float val = (fr ? acc1[db][r] : acc0[db][r]) * inv;
          hnew[(size_t)(b * 2048 + n) * 256 + hh * 64 + db * 16 + m] = val;
          sums[db] += val;
          sqs[db] += val * val;
        }
      }
    }
#pragma unroll
    for (int db = 0; db < 4; db++) {
      sums[db] += __shfl_xor(sums[db], 16); sums[db] += __shfl_xor(sums[db], 32);
      sqs[db]  += __shfl_xor(sqs[db], 16);  sqs[db]  += __shfl_xor(sqs[db], 32);
    }
    if (g == 0) {
#pragma unroll
      for (int db = 0; db < 4; db++) {
        atomicAdd(&chsum[hh * 64 + db * 16 + m], sums[db]);
        atomicAdd(&chsq[hh * 64 + db * 16 + m], sqs[db]);
      }
    }
  }
#undef WRPART
#undef ADDPART
}

// ---------------- Kernel D: BN(+stats inline) + ELU -----------------------
__global__ __launch_bounds__(256) void k_bn_elu(const float* __restrict__ hnew,
                                                const float* __restrict__ chsum,
                                                const float* __restrict__ chsq,
                                                const float* __restrict__ gamma,
                                                const float* __restrict__ beta,
                                                float* __restrict__ out) {
  int idx4 = blockIdx.x * 256 + threadIdx.x;
  f32x4 x = ((const f32x4*)hnew)[idx4];
  int c0 = (idx4 * 4) & 255;
  f32x4 s = *(const f32x4*)(chsum + c0);
  f32x4 sq = *(const f32x4*)(chsq + c0);
  f32x4 gm = *(const f32x4*)(gamma + c0);
  f32x4 bt = *(const f32x4*)(beta + c0);
  f32x4 y;
#pragma unroll
  for (int e = 0; e < 4; e++) {
    float mean = s[e] * (1.0f / 8192.0f);
    float var = sq[e] * (1.0f / 8192.0f) - mean * mean;
    float sc = gm[e] * rsqrtf(var + BNEPS);
    float v = (x[e] - mean) * sc + bt[e];
    y[e] = v > 0.f ? v : expm1f(v);
  }
  ((f32x4*)out)[idx4] = y;
}

extern "C" void kernel_launch(void* const* d_in, const int* in_sizes, int n_in,
                              void* d_out, int out_size, void* d_ws, size_t ws_size,
                              hipStream_t stream) {
  const float* h = (const float*)d_in[0];
  const float* W = (const float*)d_in[1];
  const float* a = (const float*)d_in[2];
  const float* gamma = (const float*)d_in[3];
  const float* beta = (const float*)d_in[4];
  const int* adj = (const int*)d_in[5];

  char* ws = (char*)d_ws;
  unsigned* adjb = (unsigned*)ws;                                  // 512 KB
  unsigned short* wht = (unsigned short*)(ws + (512 << 10));       // 4 MB
  float* src = (float*)(ws + (512 << 10) + (4 << 20));             // 128 KB
  float* dst = src + 16 * 2048;                                    // 128 KB
  float* chsum = dst + 16 * 2048;                                  // 256
  float* chsq = chsum + 256;                                       // 256
  unsigned* dmaxU = (unsigned*)(chsq + 256);                       // 64
  float* hnew = (float*)(ws + (512 << 10) + (5 << 20));            // 8 MB

  k_pack_adj<<<(N_ * N_) / 256, 256, 0, stream>>>(adj, adjb, chsum);
  k_gemm<<<(B_ * N_) / 16, 256, 0, stream>>>(h, W, a, wht, src, dst, dmaxU);
  k_attn<<<B_ * H_ * (N_ / 32), 256, 0, stream>>>(adjb, wht, src, dst, dmaxU,
                                                  hnew, chsum, chsq);
  k_bn_elu<<<(B_ * N_ * HD_) / 1024, 256, 0, stream>>>(hnew, chsum, chsq,
                                                       gamma, beta, (float*)d_out);
}

// Round 7
// 73.823 us; speedup vs baseline: 1.2084x; 1.2084x over previous
//
#include <hip/hip_runtime.h>

#define B_ 4
#define N_ 2048
#define IND_ 128
#define H_ 4
#define D_ 64
#define HD_ 256
#define LEAKY 0.2f
#define BNEPS 1e-5f
#define LOG2E 1.44269504088896340736f

typedef float f32x4 __attribute__((ext_vector_type(4)));
typedef short s16x8 __attribute__((ext_vector_type(8)));
typedef unsigned int u32x4 __attribute__((ext_vector_type(4)));

static __device__ __forceinline__ unsigned short f2bf(float f) {
  unsigned u = __builtin_bit_cast(unsigned, f);
  u = (u + 0x7fffu + ((u >> 16) & 1u)) >> 16;   // RNE
  return (unsigned short)u;
}
static __device__ __forceinline__ unsigned encf(float f) {
  unsigned u = __builtin_bit_cast(unsigned, f);
  return (u & 0x80000000u) ? ~u : (u | 0x80000000u);
}
static __device__ __forceinline__ float decf(unsigned u) {
  unsigned b = (u & 0x80000000u) ? (u ^ 0x80000000u) : ~u;
  return __builtin_bit_cast(float, b);
}

// ------- Kernel A: pack adjacency + zero accumulators + W^T bf16 ----------
__global__ __launch_bounds__(256) void k_pack_adj(const int* __restrict__ adj,
                                                  unsigned* __restrict__ bits,
                                                  float* __restrict__ zbuf,
                                                  const float* __restrict__ W,
                                                  unsigned short* __restrict__ wt) {
  if (blockIdx.x == 0) {
    for (int i = threadIdx.x; i < 576; i += 256) zbuf[i] = 0.f;
  }
  // blocks 0..127: transpose W[k][ch] f32 -> wt[ch][k] bf16 (64KB, built once)
  if (blockIdx.x < 128) {
    int kb = blockIdx.x;
    wt[(size_t)threadIdx.x * 128 + kb] = f2bf(W[(size_t)kb * 256 + threadIdx.x]);
  }
  int idx = blockIdx.x * 256 + threadIdx.x;     // flat over N*N (row-major)
  int val = adj[idx] != 0;
  unsigned long long m = __ballot(val);
  int lane = threadIdx.x & 63;
  if (lane == 0)       bits[idx >> 5] = (unsigned)m;
  else if (lane == 32) bits[idx >> 5] = (unsigned)(m >> 32);
}

// ------- Kernel B: Wh^T = Wt @ h^T via MFMA (no LDS, no barriers) ---------
// 512 blocks x 16 rows(n). Wave w owns head w's 64 channels. D-layout
// (col=n, row=ch) lands directly in wht[bh][d][n]. src/dst from fp32 acc.
__global__ __launch_bounds__(256) void k_gemm(const float* __restrict__ h,
                                              const unsigned short* __restrict__ wt,
                                              const float* __restrict__ a,
                                              unsigned short* __restrict__ wht,
                                              float* __restrict__ src,
                                              float* __restrict__ dst,
                                              unsigned* __restrict__ dmaxU) {
  int t = threadIdx.x;
  int w = t >> 6, lane = t & 63, m = lane & 15, g = lane >> 4;
  int r0 = blockIdx.x * 16;                    // flat row base in [0, B*N)
  int b = r0 >> 11, n0 = r0 & 2047;
  int hh = w;

  // A-frags: wt[ch][k], ch = w*64 + chf*16 + m, k-chunk = ks*32 + g*8
  s16x8 Af[4][4];
  const s16x8* wtp = (const s16x8*)wt;
#pragma unroll
  for (int chf = 0; chf < 4; chf++) {
    int ch = w * 64 + chf * 16 + m;
#pragma unroll
    for (int ks = 0; ks < 4; ks++)
      Af[chf][ks] = wtp[(ch * 128 + ks * 32 + g * 8) >> 3];
  }
  // B-frags: h[r0+m][ks*32 + g*8 ..+8] f32 -> bf16 pack
  s16x8 Bf[4];
#pragma unroll
  for (int ks = 0; ks < 4; ks++) {
    const float* hp = h + (size_t)(r0 + m) * 128 + ks * 32 + g * 8;
    f32x4 h0 = *(const f32x4*)hp;
    f32x4 h1 = *(const f32x4*)(hp + 4);
    u32x4 bu;
#pragma unroll
    for (int e = 0; e < 4; e++) {
      float lo = (e < 2) ? h0[2 * e] : h1[2 * e - 4];
      float hi = (e < 2) ? h0[2 * e + 1] : h1[2 * e - 3];
      unsigned rr_;
      asm("v_cvt_pk_bf16_f32 %0, %1, %2" : "=v"(rr_) : "v"(lo), "v"(hi));
      bu[e] = rr_;
    }
    Bf[ks] = __builtin_bit_cast(s16x8, bu);
  }

  f32x4 acc[4];
#pragma unroll
  for (int chf = 0; chf < 4; chf++) acc[chf] = (f32x4){0.f, 0.f, 0.f, 0.f};
#pragma unroll
  for (int ks = 0; ks < 4; ks++)
#pragma unroll
    for (int chf = 0; chf < 4; chf++)
      acc[chf] = __builtin_amdgcn_mfma_f32_16x16x32_bf16(Af[chf][ks], Bf[ks], acc[chf], 0, 0, 0);

  // ---- write wht: lane holds ch = w*64 + chf*16 + g*4 + reg, n = n0 + m
  size_t obase = ((size_t)((b * 4 + hh) * 64)) * 2048 + n0 + m;
#pragma unroll
  for (int chf = 0; chf < 4; chf++) {
    int d = chf * 16 + g * 4;
#pragma unroll
    for (int reg = 0; reg < 4; reg++)
      wht[obase + (size_t)(d + reg) * 2048] = f2bf(acc[chf][reg]);
  }

  // ---- src/dst scalars for head hh from fp32 acc (pre-scaled by log2e)
  float sv = 0.f, dv = 0.f;
#pragma unroll
  for (int chf = 0; chf < 4; chf++)
#pragma unroll
    for (int reg = 0; reg < 4; reg++) {
      int d = chf * 16 + g * 4 + reg;
      float whv = acc[chf][reg];
      sv = fmaf(whv, a[hh * 128 + d] * LOG2E, sv);
      dv = fmaf(whv, a[hh * 128 + 64 + d] * LOG2E, dv);
    }
  sv += __shfl_xor(sv, 16); sv += __shfl_xor(sv, 32);
  dv += __shfl_xor(dv, 16); dv += __shfl_xor(dv, 32);
  if (g == 0) {
    src[(size_t)(b * 4 + hh) * 2048 + n0 + m] = sv;
    dst[(size_t)(b * 4 + hh) * 2048 + n0 + m] = dv;
  }
  float dmx = dv;
#pragma unroll
  for (int off = 1; off < 16; off <<= 1) dmx = fmaxf(dmx, __shfl_xor(dmx, off));
  if (lane == 0) atomicMax(&dmaxU[b * 4 + hh], encf(dmx));
}

// ---------------- Kernel C: flash attention, factorized scores ------------
// p = max(A_i*u_j, B_i*v_j): no transcendental in the inner loop.
// Denominator via 5th MFMA (af x ones) -> lands per-row in accd[r].
// 512 threads: waves 0-3 j in [0,1024), waves 4-7 j in [1024,2048).
__global__ __launch_bounds__(512) void k_attn(const unsigned* __restrict__ adjb,
                                              const unsigned short* __restrict__ wht,
                                              const float* __restrict__ src,
                                              const float* __restrict__ dst,
                                              const unsigned* __restrict__ dmaxU,
                                              float* __restrict__ hnew,
                                              float* __restrict__ chsum,
                                              float* __restrict__ chsq) {
  __shared__ unsigned adj_lds[64 * 65];   // 16.6KB; reused as f32 acc-combine buf
  __shared__ u32x4 whb4[2048];            // 2 halves x 2 dbuf x 8KB, XOR-swizzled
  __shared__ float ul[2048], vl[2048];    // 16KB: u_j = 2^dstL, v_j = 2^(.2 dstL)
  __shared__ float redS[256], redQ[256];

  int t = threadIdx.x;
  int bid = blockIdx.x;
  int bh = bid & 15, it = bid >> 4;       // 16 consecutive blocks share adj rows (L2)
  int b = bh >> 2, hh = bh & 3;
  int i0 = it * 64;
  int w8 = t >> 6, half = w8 >> 2, w = w8 & 3;
  int lane = t & 63, m = lane & 15, g = lane >> 4;

  for (int idx = t; idx < 64 * 64; idx += 512) {
    int r = idx >> 6, wd = idx & 63;
    adj_lds[r * 65 + wd] = adjb[(size_t)(i0 + r) * 64 + wd];
  }
  {
    f32x4 dv = ((const f32x4*)(dst + (size_t)bh * 2048))[t];
    f32x4 uu, vv;
#pragma unroll
    for (int e = 0; e < 4; e++) {
      uu[e] = __builtin_amdgcn_exp2f(dv[e]);
      vv[e] = __builtin_amdgcn_exp2f(0.2f * dv[e]);
    }
    ((f32x4*)ul)[t] = uu;
    ((f32x4*)vl)[t] = vv;
  }

  int row_i = i0 + w * 16 + m;            // A-operand row this lane fills
  float srcL = src[(size_t)bh * 2048 + row_i];
  float dmaxL = decf(dmaxU[bh]);
  float sML = srcL + dmaxL;
  float negM = -fmaxf(sML, LEAKY * sML);  // -(row score upper bound), log2 domain
  float Af = __builtin_amdgcn_exp2f(srcL + negM);
  float Bf = __builtin_amdgcn_exp2f(fmaf(LEAKY, srcL, negM));

  s16x8 bones;
#pragma unroll
  for (int e = 0; e < 8; e++) bones[e] = (short)0x3F80;   // bf16 1.0

  f32x4 acc[4], accd;
#pragma unroll
  for (int db = 0; db < 4; db++) acc[db] = (f32x4){0.f, 0.f, 0.f, 0.f};
  accd = (f32x4){0.f, 0.f, 0.f, 0.f};

  char* wbase = (char*)whb4 + half * 16384;
  int ts = t & 255;
  int r_ = ts >> 2, ch_ = ts & 3;
  int jtbase = half * 16;
  const char* gbase = (const char*)(wht + (size_t)(bh * 64 + r_) * 2048) + jtbase * 128;
  int sw = (r_ & 7) << 4;
  u32x4 R0, R1;

#define LOADT(jt_) { const u32x4* gp = (const u32x4*)(gbase + (jt_) * 128 + ch_ * 32); \
                     R0 = gp[0]; R1 = gp[1]; }
#define WRITET(pb_) { char* wb_ = (pb_); \
                      *(u32x4*)(wb_ + r_ * 128 + ((ch_ * 32) ^ sw)) = R0; \
                      *(u32x4*)(wb_ + r_ * 128 + ((ch_ * 32 + 16) ^ sw)) = R1; }

  LOADT(0); WRITET(wbase); LOADT(1);

  for (int jt = 0; jt < 16; jt++) {
    int cur = jt & 1;
    __syncthreads();                      // drains prefetch vmem + dbuf writes
    if (jt < 15) WRITET(wbase + (cur ^ 1) * 8192);   // tile jt+1 -> other buf
    if (jt < 14) LOADT(jt + 2);                      // issue tile jt+2 loads
    const char* wbufc = wbase + cur * 8192;
    int jglob = jtbase + jt;

#pragma unroll
    for (int ks = 0; ks < 2; ks++) {
      unsigned adjw = adj_lds[(w * 16 + m) * 65 + jglob * 2 + ks];
      unsigned bits = (adjw >> (g * 8)) & 0xffu;
      const float* up = &ul[jglob * 64 + ks * 32 + g * 8];
      const float* vp = &vl[jglob * 64 + ks * 32 + g * 8];
      f32x4 u0 = *(const f32x4*)up, u1 = *(const f32x4*)(up + 4);
      f32x4 v0 = *(const f32x4*)vp, v1 = *(const f32x4*)(vp + 4);
      float pm[8];
#pragma unroll
      for (int e = 0; e < 8; e++) {
        float ue = (e < 4) ? u0[e] : u1[e - 4];
        float ve = (e < 4) ? v0[e] : v1[e - 4];
        float p = fmaxf(Af * ue, Bf * ve);            // leaky-exp, factorized
        unsigned keep = (unsigned)(((int)(bits << (31 - e))) >> 31);
        pm[e] = __builtin_bit_cast(float, __builtin_bit_cast(unsigned, p) & keep);
      }
      u32x4 afu;
#pragma unroll
      for (int e2 = 0; e2 < 4; e2++) {
        unsigned rr_;
        asm("v_cvt_pk_bf16_f32 %0, %1, %2" : "=v"(rr_) : "v"(pm[2 * e2]), "v"(pm[2 * e2 + 1]));
        afu[e2] = rr_;
      }
      s16x8 af = __builtin_bit_cast(s16x8, afu);
#pragma unroll
      for (int db = 0; db < 4; db++) {
        int dl = db * 16 + m;
        int off = dl * 128 + ((ks * 64 + g * 16) ^ ((dl & 7) << 4));
        s16x8 bf = *(const s16x8*)(wbufc + off);
        acc[db] = __builtin_amdgcn_mfma_f32_16x16x32_bf16(af, bf, acc[db], 0, 0, 0);
      }
      accd = __builtin_amdgcn_mfma_f32_16x16x32_bf16(af, bones, accd, 0, 0, 0);
    }
  }
#undef LOADT
#undef WRITET

  __syncthreads();                        // both halves done with adj_lds reads
  float* accl = (float*)adj_lds;          // reuse: [row][65] (col 64 = den)
  if (half == 1) {
#pragma unroll
    for (int db = 0; db < 4; db++)
#pragma unroll
      for (int r = 0; r < 4; r++)
        accl[(w * 16 + 4 * g + r) * 65 + db * 16 + m] = acc[db][r];
    if (m == 0) {
#pragma unroll
      for (int r = 0; r < 4; r++)
        accl[(w * 16 + 4 * g + r) * 65 + 64] = accd[r];
    }
  }
  __syncthreads();

  if (half == 0) {
#pragma unroll
    for (int db = 0; db < 4; db++)
#pragma unroll
      for (int r = 0; r < 4; r++)
        acc[db][r] += accl[(w * 16 + 4 * g + r) * 65 + db * 16 + m];
    float inv[4];
#pragma unroll
    for (int r = 0; r < 4; r++) {
      float dtot = accd[r] + accl[(w * 16 + 4 * g + r) * 65 + 64];
      inv[r] = dtot > 0.f ? 1.0f / dtot : 0.f;  // all-masked row -> zeros
    }

    float sums[4] = {0.f, 0.f, 0.f, 0.f}, sqs[4] = {0.f, 0.f, 0.f, 0.f};
#pragma unroll
    for (int r = 0; r < 4; r++) {
      int n = i0 + w * 16 + 4 * g + r;
#pragma unroll
      for (int db = 0; db < 4; db++) {
        float val = acc[db][r] * inv[r];
        hnew[(size_t)(b * 2048 + n) * 256 + hh * 64 + db * 16 + m] = val;
        sums[db] += val;
        sqs[db] += val * val;
      }
    }
#pragma unroll
    for (int db = 0; db < 4; db++) {
      sums[db] += __shfl_xor(sums[db], 16); sums[db] += __shfl_xor(sums[db], 32);
      sqs[db]  += __shfl_xor(sqs[db], 16);  sqs[db]  += __shfl_xor(sqs[db], 32);
    }
    if (g == 0) {
#pragma unroll
      for (int db = 0; db < 4; db++) {
        redS[w * 64 + db * 16 + m] = sums[db];
        redQ[w * 64 + db * 16 + m] = sqs[db];
      }
    }
  }
  __syncthreads();
  if (t < 64) {
    float ts2 = redS[t] + redS[64 + t] + redS[128 + t] + redS[192 + t];
    float tq = redQ[t] + redQ[64 + t] + redQ[128 + t] + redQ[192 + t];
    atomicAdd(&chsum[hh * 64 + t], ts2);
    atomicAdd(&chsq[hh * 64 + t], tq);
  }
}

// ---------------- Kernel D: BN(+stats inline) + ELU -----------------------
__global__ __launch_bounds__(256) void k_bn_elu(const float* __restrict__ hnew,
                                                const float* __restrict__ chsum,
                                                const float* __restrict__ chsq,
                                                const float* __restrict__ gamma,
                                                const float* __restrict__ beta,
                                                float* __restrict__ out) {
  int idx4 = blockIdx.x * 256 + threadIdx.x;
  f32x4 x = ((const f32x4*)hnew)[idx4];
  int c0 = (idx4 * 4) & 255;
  f32x4 s = *(const f32x4*)(chsum + c0);
  f32x4 sq = *(const f32x4*)(chsq + c0);
  f32x4 gm = *(const f32x4*)(gamma + c0);
  f32x4 bt = *(const f32x4*)(beta + c0);
  f32x4 y;
#pragma unroll
  for (int e = 0; e < 4; e++) {
    float mean = s[e] * (1.0f / 8192.0f);
    float var = sq[e] * (1.0f / 8192.0f) - mean * mean;
    float sc = gm[e] * rsqrtf(var + BNEPS);
    float v = (x[e] - mean) * sc + bt[e];
    y[e] = v > 0.f ? v : expm1f(v);
  }
  ((f32x4*)out)[idx4] = y;
}

extern "C" void kernel_launch(void* const* d_in, const int* in_sizes, int n_in,
                              void* d_out, int out_size, void* d_ws, size_t ws_size,
                              hipStream_t stream) {
  const float* h = (const float*)d_in[0];
  const float* W = (const float*)d_in[1];
  const float* a = (const float*)d_in[2];
  const float* gamma = (const float*)d_in[3];
  const float* beta = (const float*)d_in[4];
  const int* adj = (const int*)d_in[5];

  char* ws = (char*)d_ws;
  unsigned* adjb = (unsigned*)ws;                                  // 512 KB
  unsigned short* wht = (unsigned short*)(ws + (512 << 10));       // 4 MB
  float* src = (float*)(ws + (512 << 10) + (4 << 20));             // 128 KB
  float* dst = src + 16 * 2048;                                    // 128 KB
  float* chsum = dst + 16 * 2048;                                  // 256
  float* chsq = chsum + 256;                                       // 256
  unsigned* dmaxU = (unsigned*)(chsq + 256);                       // 64
  unsigned short* wt = (unsigned short*)(ws + (512 << 10) + (4 << 20) + (512 << 10)); // 64KB
  float* hnew = (float*)(ws + (512 << 10) + (5 << 20));            // 8 MB

  k_pack_adj<<<(N_ * N_) / 256, 256, 0, stream>>>(adj, adjb, chsum, W, wt);
  k_gemm<<<(B_ * N_) / 16, 256, 0, stream>>>(h, wt, a, wht, src, dst, dmaxU);
  k_attn<<<B_ * H_ * (N_ / 64), 512, 0, stream>>>(adjb, wht, src, dst, dmaxU,
                                                  hnew, chsum, chsq);
  k_bn_elu<<<(B_ * N_ * HD_) / 1024, 256, 0, stream>>>(hnew, chsum, chsq,
                                                       gamma, beta, (float*)d_out);
}

// Round 8
// 57.860 us; speedup vs baseline: 1.5418x; 1.2759x over previous
//
#include <hip/hip_runtime.h>

#define B_ 4
#define N_ 2048
#define IND_ 128
#define H_ 4
#define D_ 64
#define HD_ 256
#define LEAKY 0.2f
#define BNEPS 1e-5f
#define LOG2E 1.44269504088896340736f

typedef float f32x4 __attribute__((ext_vector_type(4)));
typedef short s16x8 __attribute__((ext_vector_type(8)));
typedef unsigned int u32x4 __attribute__((ext_vector_type(4)));

static __device__ __forceinline__ unsigned short f2bf(float f) {
  unsigned u = __builtin_bit_cast(unsigned, f);
  u = (u + 0x7fffu + ((u >> 16) & 1u)) >> 16;   // RNE
  return (unsigned short)u;
}

// ------- Kernel A: pack adjacency + zero accumulators + W^T bf16 ----------
__global__ __launch_bounds__(256) void k_pack_adj(const int* __restrict__ adj,
                                                  unsigned* __restrict__ bits,
                                                  float* __restrict__ zbuf,
                                                  const float* __restrict__ W,
                                                  unsigned short* __restrict__ wt) {
  if (blockIdx.x == 0) {
    for (int i = threadIdx.x; i < 512; i += 256) zbuf[i] = 0.f;  // chsum|chsq
  }
  // blocks 0..127: transpose W[k][ch] f32 -> wt[ch][k] bf16 (64KB, built once)
  if (blockIdx.x < 128) {
    int kb = blockIdx.x;
    wt[(size_t)threadIdx.x * 128 + kb] = f2bf(W[(size_t)kb * 256 + threadIdx.x]);
  }
  int idx = blockIdx.x * 256 + threadIdx.x;     // flat over N*N (row-major)
  int val = adj[idx] != 0;
  unsigned long long m = __ballot(val);
  int lane = threadIdx.x & 63;
  if (lane == 0)       bits[idx >> 5] = (unsigned)m;
  else if (lane == 32) bits[idx >> 5] = (unsigned)(m >> 32);
}

// ------- Kernel B: Wh^T = Wt @ h^T via MFMA (no LDS, no barriers, no atomics)
// 512 blocks x 16 rows(n). Wave w owns head w's 64 channels. D-layout
// (col=n, row=ch) lands directly in wht[bh][d][n]. src/dst from fp32 acc.
__global__ __launch_bounds__(256) void k_gemm(const float* __restrict__ h,
                                              const unsigned short* __restrict__ wt,
                                              const float* __restrict__ a,
                                              unsigned short* __restrict__ wht,
                                              float* __restrict__ src,
                                              float* __restrict__ dst) {
  int t = threadIdx.x;
  int w = t >> 6, lane = t & 63, m = lane & 15, g = lane >> 4;
  int r0 = blockIdx.x * 16;                    // flat row base in [0, B*N)
  int b = r0 >> 11, n0 = r0 & 2047;
  int hh = w;

  // A-frags: wt[ch][k], ch = w*64 + chf*16 + m, k-chunk = ks*32 + g*8
  s16x8 Af[4][4];
  const s16x8* wtp = (const s16x8*)wt;
#pragma unroll
  for (int chf = 0; chf < 4; chf++) {
    int ch = w * 64 + chf * 16 + m;
#pragma unroll
    for (int ks = 0; ks < 4; ks++)
      Af[chf][ks] = wtp[(ch * 128 + ks * 32 + g * 8) >> 3];
  }
  // B-frags: h[r0+m][ks*32 + g*8 ..+8] f32 -> bf16 pack
  s16x8 Bf[4];
#pragma unroll
  for (int ks = 0; ks < 4; ks++) {
    const float* hp = h + (size_t)(r0 + m) * 128 + ks * 32 + g * 8;
    f32x4 h0 = *(const f32x4*)hp;
    f32x4 h1 = *(const f32x4*)(hp + 4);
    u32x4 bu;
#pragma unroll
    for (int e = 0; e < 4; e++) {
      float lo = (e < 2) ? h0[2 * e] : h1[2 * e - 4];
      float hi = (e < 2) ? h0[2 * e + 1] : h1[2 * e - 3];
      unsigned rr_;
      asm("v_cvt_pk_bf16_f32 %0, %1, %2" : "=v"(rr_) : "v"(lo), "v"(hi));
      bu[e] = rr_;
    }
    Bf[ks] = __builtin_bit_cast(s16x8, bu);
  }

  f32x4 acc[4];
#pragma unroll
  for (int chf = 0; chf < 4; chf++) acc[chf] = (f32x4){0.f, 0.f, 0.f, 0.f};
#pragma unroll
  for (int ks = 0; ks < 4; ks++)
#pragma unroll
    for (int chf = 0; chf < 4; chf++)
      acc[chf] = __builtin_amdgcn_mfma_f32_16x16x32_bf16(Af[chf][ks], Bf[ks], acc[chf], 0, 0, 0);

  // ---- write wht: lane holds ch = w*64 + chf*16 + g*4 + reg, n = n0 + m
  size_t obase = ((size_t)((b * 4 + hh) * 64)) * 2048 + n0 + m;
#pragma unroll
  for (int chf = 0; chf < 4; chf++) {
    int d = chf * 16 + g * 4;
#pragma unroll
    for (int reg = 0; reg < 4; reg++)
      wht[obase + (size_t)(d + reg) * 2048] = f2bf(acc[chf][reg]);
  }

  // ---- src/dst scalars for head hh from fp32 acc (pre-scaled by log2e)
  float sv = 0.f, dv = 0.f;
#pragma unroll
  for (int chf = 0; chf < 4; chf++)
#pragma unroll
    for (int reg = 0; reg < 4; reg++) {
      int d = chf * 16 + g * 4 + reg;
      float whv = acc[chf][reg];
      sv = fmaf(whv, a[hh * 128 + d] * LOG2E, sv);
      dv = fmaf(whv, a[hh * 128 + 64 + d] * LOG2E, dv);
    }
  sv += __shfl_xor(sv, 16); sv += __shfl_xor(sv, 32);
  dv += __shfl_xor(dv, 16); dv += __shfl_xor(dv, 32);
  if (g == 0) {
    src[(size_t)(b * 4 + hh) * 2048 + n0 + m] = sv;
    dst[(size_t)(b * 4 + hh) * 2048 + n0 + m] = dv;
  }
}

// ---------------- Kernel C: flash attention (256 thr, factorized) ---------
// p = max(Af_i*u_j, Bf_i*v_j); no max-shift needed (scores bounded ~2^9).
// Denominator via 5th MFMA (af x ones) -> per-row in accd[r]. 2-deep
// double-buffered LDS pipeline for Wh^T tiles.
__global__ __launch_bounds__(256) void k_attn(const unsigned* __restrict__ adjb,
                                              const unsigned short* __restrict__ wht,
                                              const float* __restrict__ src,
                                              const float* __restrict__ dst,
                                              float* __restrict__ hnew,
                                              float* __restrict__ chsum,
                                              float* __restrict__ chsq) {
  __shared__ unsigned adj_lds[64 * 65];   // 16.6KB, padded
  __shared__ u32x4 whb4[1024];            // 2 x 8KB dbuf, XOR-swizzled
  __shared__ float ul[2048], vl[2048];    // 16KB: u_j = 2^dstL, v_j = 2^(.2 dstL)
  __shared__ float redS[256], redQ[256];

  int t = threadIdx.x;
  int bid = blockIdx.x;
  int bh = bid & 15, it = bid >> 4;       // 16 consecutive blocks share adj rows (L2)
  int b = bh >> 2, hh = bh & 3;
  int i0 = it * 64;
  int w = t >> 6, lane = t & 63, m = lane & 15, g = lane >> 4;

  for (int idx = t; idx < 64 * 64; idx += 256) {
    int r = idx >> 6, wd = idx & 63;
    adj_lds[r * 65 + wd] = adjb[(size_t)(i0 + r) * 64 + wd];
  }
  {
    const f32x4* dg = (const f32x4*)(dst + (size_t)bh * 2048);
    f32x4 d0 = dg[2 * t], d1 = dg[2 * t + 1];
    f32x4 u0, u1, v0, v1;
#pragma unroll
    for (int e = 0; e < 4; e++) {
      u0[e] = __builtin_amdgcn_exp2f(d0[e]);
      v0[e] = __builtin_amdgcn_exp2f(0.2f * d0[e]);
      u1[e] = __builtin_amdgcn_exp2f(d1[e]);
      v1[e] = __builtin_amdgcn_exp2f(0.2f * d1[e]);
    }
    ((f32x4*)ul)[2 * t] = u0;  ((f32x4*)ul)[2 * t + 1] = u1;
    ((f32x4*)vl)[2 * t] = v0;  ((f32x4*)vl)[2 * t + 1] = v1;
  }

  float srcL = src[(size_t)bh * 2048 + i0 + w * 16 + m];   // A-frag row
  float Af = __builtin_amdgcn_exp2f(srcL);
  float Bf = __builtin_amdgcn_exp2f(LEAKY * srcL);

  s16x8 bones;
#pragma unroll
  for (int e = 0; e < 8; e++) bones[e] = (short)0x3F80;    // bf16 1.0

  f32x4 acc[4], accd;
#pragma unroll
  for (int db = 0; db < 4; db++) acc[db] = (f32x4){0.f, 0.f, 0.f, 0.f};
  accd = (f32x4){0.f, 0.f, 0.f, 0.f};

  char* wbase = (char*)whb4;
  int r_ = t >> 2, ch_ = t & 3;
  const char* gbase = (const char*)(wht + (size_t)(bh * 64 + r_) * 2048);
  int sw = (r_ & 7) << 4;
  u32x4 R0, R1;

#define LOADT(jt_) { const u32x4* gp = (const u32x4*)(gbase + (size_t)(jt_) * 128 + ch_ * 32); \
                     R0 = gp[0]; R1 = gp[1]; }
#define WRITET(pb_) { char* wb_ = (pb_); \
                      *(u32x4*)(wb_ + r_ * 128 + ((ch_ * 32) ^ sw)) = R0; \
                      *(u32x4*)(wb_ + r_ * 128 + ((ch_ * 32 + 16) ^ sw)) = R1; }

  LOADT(0); WRITET(wbase); LOADT(1);

  for (int jt = 0; jt < 32; jt++) {
    int cur = jt & 1;
    __syncthreads();                      // drains prefetch vmem + dbuf writes
    if (jt < 31) WRITET(wbase + (cur ^ 1) * 8192);   // tile jt+1 -> other buf
    if (jt < 30) LOADT(jt + 2);                      // issue tile jt+2 loads
    const char* wbufc = wbase + cur * 8192;

#pragma unroll
    for (int ks = 0; ks < 2; ks++) {
      unsigned adjw = adj_lds[(w * 16 + m) * 65 + jt * 2 + ks];
      unsigned bits = (adjw >> (g * 8)) & 0xffu;
      const float* up = &ul[jt * 64 + ks * 32 + g * 8];
      const float* vp = &vl[jt * 64 + ks * 32 + g * 8];
      f32x4 u0 = *(const f32x4*)up, u1 = *(const f32x4*)(up + 4);
      f32x4 v0 = *(const f32x4*)vp, v1 = *(const f32x4*)(vp + 4);
      float pm[8];
#pragma unroll
      for (int e = 0; e < 8; e++) {
        float ue = (e < 4) ? u0[e] : u1[e - 4];
        float ve = (e < 4) ? v0[e] : v1[e - 4];
        float p = fmaxf(Af * ue, Bf * ve);            // leaky-exp, factorized
        unsigned keep = (unsigned)(((int)(bits << (31 - e))) >> 31);
        pm[e] = __builtin_bit_cast(float, __builtin_bit_cast(unsigned, p) & keep);
      }
      u32x4 afu;
#pragma unroll
      for (int e2 = 0; e2 < 4; e2++) {
        unsigned rr_;
        asm("v_cvt_pk_bf16_f32 %0, %1, %2" : "=v"(rr_) : "v"(pm[2 * e2]), "v"(pm[2 * e2 + 1]));
        afu[e2] = rr_;
      }
      s16x8 af = __builtin_bit_cast(s16x8, afu);
#pragma unroll
      for (int db = 0; db < 4; db++) {
        int dl = db * 16 + m;
        int off = dl * 128 + ((ks * 64 + g * 16) ^ ((dl & 7) << 4));
        s16x8 bf = *(const s16x8*)(wbufc + off);
        acc[db] = __builtin_amdgcn_mfma_f32_16x16x32_bf16(af, bf, acc[db], 0, 0, 0);
      }
      accd = __builtin_amdgcn_mfma_f32_16x16x32_bf16(af, bones, accd, 0, 0, 0);
    }
  }
#undef LOADT
#undef WRITET

  // accd[r] = denominator of row i0 + w*16 + 4g + r (uniform across m)
  float sums[4] = {0.f, 0.f, 0.f, 0.f}, sqs[4] = {0.f, 0.f, 0.f, 0.f};
#pragma unroll
  for (int r = 0; r < 4; r++) {
    float inv = accd[r] > 0.f ? 1.0f / accd[r] : 0.f;   // all-masked -> zeros
    int n = i0 + w * 16 + 4 * g + r;
#pragma unroll
    for (int db = 0; db < 4; db++) {
      float val = acc[db][r] * inv;
      hnew[(size_t)(b * 2048 + n) * 256 + hh * 64 + db * 16 + m] = val;
      sums[db] += val;
      sqs[db] += val * val;
    }
  }
#pragma unroll
  for (int db = 0; db < 4; db++) {
    sums[db] += __shfl_xor(sums[db], 16); sums[db] += __shfl_xor(sums[db], 32);
    sqs[db]  += __shfl_xor(sqs[db], 16);  sqs[db]  += __shfl_xor(sqs[db], 32);
  }
  if (g == 0) {
#pragma unroll
    for (int db = 0; db < 4; db++) {
      redS[w * 64 + db * 16 + m] = sums[db];
      redQ[w * 64 + db * 16 + m] = sqs[db];
    }
  }
  __syncthreads();
  if (t < 64) {
    float ts2 = redS[t] + redS[64 + t] + redS[128 + t] + redS[192 + t];
    float tq = redQ[t] + redQ[64 + t] + redQ[128 + t] + redQ[192 + t];
    atomicAdd(&chsum[hh * 64 + t], ts2);
    atomicAdd(&chsq[hh * 64 + t], tq);
  }
}

// ---------------- Kernel D: BN(+stats inline) + ELU -----------------------
__global__ __launch_bounds__(256) void k_bn_elu(const float* __restrict__ hnew,
                                                const float* __restrict__ chsum,
                                                const float* __restrict__ chsq,
                                                const float* __restrict__ gamma,
                                                const float* __restrict__ beta,
                                                float* __restrict__ out) {
  int idx4 = blockIdx.x * 256 + threadIdx.x;
  f32x4 x = ((const f32x4*)hnew)[idx4];
  int c0 = (idx4 * 4) & 255;
  f32x4 s = *(const f32x4*)(chsum + c0);
  f32x4 sq = *(const f32x4*)(chsq + c0);
  f32x4 gm = *(const f32x4*)(gamma + c0);
  f32x4 bt = *(const f32x4*)(beta + c0);
  f32x4 y;
#pragma unroll
  for (int e = 0; e < 4; e++) {
    float mean = s[e] * (1.0f / 8192.0f);
    float var = sq[e] * (1.0f / 8192.0f) - mean * mean;
    float sc = gm[e] * rsqrtf(var + BNEPS);
    float v = (x[e] - mean) * sc + bt[e];
    y[e] = v > 0.f ? v : expm1f(v);
  }
  ((f32x4*)out)[idx4] = y;
}

extern "C" void kernel_launch(void* const* d_in, const int* in_sizes, int n_in,
                              void* d_out, int out_size, void* d_ws, size_t ws_size,
                              hipStream_t stream) {
  const float* h = (const float*)d_in[0];
  const float* W = (const float*)d_in[1];
  const float* a = (const float*)d_in[2];
  const float* gamma = (const float*)d_in[3];
  const float* beta = (const float*)d_in[4];
  const int* adj = (const int*)d_in[5];

  char* ws = (char*)d_ws;
  unsigned* adjb = (unsigned*)ws;                                  // 512 KB
  unsigned short* wht = (unsigned short*)(ws + (512 << 10));       // 4 MB
  float* src = (float*)(ws + (512 << 10) + (4 << 20));             // 128 KB
  float* dst = src + 16 * 2048;                                    // 128 KB
  float* chsum = dst + 16 * 2048;                                  // 256
  float* chsq = chsum + 256;                                       // 256
  unsigned short* wt = (unsigned short*)(ws + (512 << 10) + (4 << 20) + (512 << 10)); // 64KB
  float* hnew = (float*)(ws + (512 << 10) + (5 << 20));            // 8 MB

  k_pack_adj<<<(N_ * N_) / 256, 256, 0, stream>>>(adj, adjb, chsum, W, wt);
  k_gemm<<<(B_ * N_) / 16, 256, 0, stream>>>(h, wt, a, wht, src, dst);
  k_attn<<<B_ * H_ * (N_ / 64), 256, 0, stream>>>(adjb, wht, src, dst,
                                                  hnew, chsum, chsq);
  k_bn_elu<<<(B_ * N_ * HD_) / 1024, 256, 0, stream>>>(hnew, chsum, chsq,
                                                       gamma, beta, (float*)d_out);
}

// Round 9
// 50.646 us; speedup vs baseline: 1.7614x; 1.1425x over previous
//
#include <hip/hip_runtime.h>

#define B_ 4
#define N_ 2048
#define IND_ 128
#define H_ 4
#define D_ 64
#define HD_ 256
#define LEAKY 0.2f
#define BNEPS 1e-5f
#define LOG2E 1.44269504088896340736f

typedef float f32x4 __attribute__((ext_vector_type(4)));
typedef short s16x8 __attribute__((ext_vector_type(8)));
typedef unsigned int u32x4 __attribute__((ext_vector_type(4)));

static __device__ __forceinline__ unsigned short f2bf(float f) {
  unsigned u = __builtin_bit_cast(unsigned, f);
  u = (u + 0x7fffu + ((u >> 16) & 1u)) >> 16;   // RNE
  return (unsigned short)u;
}

// ------- Kernel A (fused): [gemm blocks 0..511] || [pack blocks 512..] ----
// gemm role: Wh^T = W^T @ h^T via MFMA, A-frags read straight from W (L2).
// D-layout (col=n, row=ch) lands directly in wht[bh][d][n]; src/dst (log2e-
// scaled) from fp32 acc. pack role: adjacency bitmask + zero accumulators.
__global__ __launch_bounds__(256) void k_pre(const int* __restrict__ adj,
                                             const float* __restrict__ W,
                                             const float* __restrict__ h,
                                             const float* __restrict__ a,
                                             unsigned* __restrict__ bits,
                                             float* __restrict__ zbuf,
                                             unsigned short* __restrict__ wht,
                                             float* __restrict__ src,
                                             float* __restrict__ dst) {
  int t = threadIdx.x;
  if (blockIdx.x >= 512) {          // ---- pack role
    int pidx = blockIdx.x - 512;
    if (pidx == 0) {
      for (int i = t; i < 512; i += 256) zbuf[i] = 0.f;   // chsum|chsq
    }
    int idx = pidx * 256 + t;       // flat over N*N (row-major)
    int val = adj[idx] != 0;
    unsigned long long mm = __ballot(val);
    int lane = t & 63;
    if (lane == 0)       bits[idx >> 5] = (unsigned)mm;
    else if (lane == 32) bits[idx >> 5] = (unsigned)(mm >> 32);
    return;
  }
  // ---- gemm role: 512 blocks x 16 rows(n); wave w owns head w's 64 ch
  int w = t >> 6, lane = t & 63, m = lane & 15, g = lane >> 4;
  int r0 = blockIdx.x * 16;                    // flat row base in [0, B*N)
  int b = r0 >> 11, n0 = r0 & 2047;
  int hh = w;

  // A-frags direct from W[k][ch]: ch = w*64+chf*16+m, k = ks*32+g*8+e
  s16x8 Af[4][4];
#pragma unroll
  for (int chf = 0; chf < 4; chf++) {
    int chl = w * 64 + chf * 16 + m;
#pragma unroll
    for (int ks = 0; ks < 4; ks++) {
      int k0 = ks * 32 + g * 8;
      u32x4 au;
#pragma unroll
      for (int e2 = 0; e2 < 4; e2++) {
        float lo = W[(size_t)(k0 + 2 * e2) * 256 + chl];
        float hi = W[(size_t)(k0 + 2 * e2 + 1) * 256 + chl];
        unsigned rr_;
        asm("v_cvt_pk_bf16_f32 %0, %1, %2" : "=v"(rr_) : "v"(lo), "v"(hi));
        au[e2] = rr_;
      }
      Af[chf][ks] = __builtin_bit_cast(s16x8, au);
    }
  }
  // B-frags: h[r0+m][ks*32 + g*8 ..+8] f32 -> bf16 pack
  s16x8 Bf[4];
#pragma unroll
  for (int ks = 0; ks < 4; ks++) {
    const float* hp = h + (size_t)(r0 + m) * 128 + ks * 32 + g * 8;
    f32x4 h0 = *(const f32x4*)hp;
    f32x4 h1 = *(const f32x4*)(hp + 4);
    u32x4 bu;
#pragma unroll
    for (int e = 0; e < 4; e++) {
      float lo = (e < 2) ? h0[2 * e] : h1[2 * e - 4];
      float hi = (e < 2) ? h0[2 * e + 1] : h1[2 * e - 3];
      unsigned rr_;
      asm("v_cvt_pk_bf16_f32 %0, %1, %2" : "=v"(rr_) : "v"(lo), "v"(hi));
      bu[e] = rr_;
    }
    Bf[ks] = __builtin_bit_cast(s16x8, bu);
  }

  f32x4 acc[4];
#pragma unroll
  for (int chf = 0; chf < 4; chf++) acc[chf] = (f32x4){0.f, 0.f, 0.f, 0.f};
#pragma unroll
  for (int ks = 0; ks < 4; ks++)
#pragma unroll
    for (int chf = 0; chf < 4; chf++)
      acc[chf] = __builtin_amdgcn_mfma_f32_16x16x32_bf16(Af[chf][ks], Bf[ks], acc[chf], 0, 0, 0);

  // write wht: lane holds ch = w*64 + chf*16 + g*4 + reg, n = n0 + m
  size_t obase = ((size_t)((b * 4 + hh) * 64)) * 2048 + n0 + m;
#pragma unroll
  for (int chf = 0; chf < 4; chf++) {
    int d = chf * 16 + g * 4;
#pragma unroll
    for (int reg = 0; reg < 4; reg++)
      wht[obase + (size_t)(d + reg) * 2048] = f2bf(acc[chf][reg]);
  }

  // src/dst scalars for head hh from fp32 acc (pre-scaled by log2e)
  float sv = 0.f, dv = 0.f;
#pragma unroll
  for (int chf = 0; chf < 4; chf++)
#pragma unroll
    for (int reg = 0; reg < 4; reg++) {
      int d = chf * 16 + g * 4 + reg;
      float whv = acc[chf][reg];
      sv = fmaf(whv, a[hh * 128 + d] * LOG2E, sv);
      dv = fmaf(whv, a[hh * 128 + 64 + d] * LOG2E, dv);
    }
  sv += __shfl_xor(sv, 16); sv += __shfl_xor(sv, 32);
  dv += __shfl_xor(dv, 16); dv += __shfl_xor(dv, 32);
  if (g == 0) {
    src[(size_t)(b * 4 + hh) * 2048 + n0 + m] = sv;
    dst[(size_t)(b * 4 + hh) * 2048 + n0 + m] = dv;
  }
}

// ---------------- Kernel C: flash attention, j split across wave-halves ---
// 512 threads: waves 0-3 handle j in [0,1024), waves 4-7 j in [1024,2048),
// each half with its own double-buffered Wh tile pipeline. Factorized
// scores p = max(Af_i*u_j, Bf_i*v_j) (no max-shift; products bounded).
// Denominator via 5th MFMA; partials combined through LDS at the end.
__global__ __launch_bounds__(512) void k_attn(const unsigned* __restrict__ adjb,
                                              const unsigned short* __restrict__ wht,
                                              const float* __restrict__ src,
                                              const float* __restrict__ dst,
                                              float* __restrict__ hnew,
                                              float* __restrict__ chsum,
                                              float* __restrict__ chsq) {
  __shared__ unsigned adj_lds[64 * 65];   // 16.6KB; reused as f32 acc-combine buf
  __shared__ u32x4 whb4[2048];            // 2 halves x 2 dbuf x 8KB, XOR-swizzled
  __shared__ float ul[2048], vl[2048];    // 16KB: u_j = 2^dstL, v_j = 2^(.2 dstL)
  __shared__ float redS[256], redQ[256];

  int t = threadIdx.x;
  int bid = blockIdx.x;
  int bh = bid & 15, it = bid >> 4;       // 16 consecutive blocks share adj rows (L2)
  int b = bh >> 2, hh = bh & 3;
  int i0 = it * 64;
  int w8 = t >> 6, half = w8 >> 2, w = w8 & 3;
  int lane = t & 63, m = lane & 15, g = lane >> 4;

  for (int idx = t; idx < 64 * 64; idx += 512) {
    int r = idx >> 6, wd = idx & 63;
    adj_lds[r * 65 + wd] = adjb[(size_t)(i0 + r) * 64 + wd];
  }
  {
    f32x4 dv = ((const f32x4*)(dst + (size_t)bh * 2048))[t];
    f32x4 uu, vv;
#pragma unroll
    for (int e = 0; e < 4; e++) {
      uu[e] = __builtin_amdgcn_exp2f(dv[e]);
      vv[e] = __builtin_amdgcn_exp2f(0.2f * dv[e]);
    }
    ((f32x4*)ul)[t] = uu;
    ((f32x4*)vl)[t] = vv;
  }

  float srcL = src[(size_t)bh * 2048 + i0 + w * 16 + m];   // A-frag row
  float Af = __builtin_amdgcn_exp2f(srcL);
  float Bf = __builtin_amdgcn_exp2f(LEAKY * srcL);

  s16x8 bones;
#pragma unroll
  for (int e = 0; e < 8; e++) bones[e] = (short)0x3F80;    // bf16 1.0

  f32x4 acc[4], accd;
#pragma unroll
  for (int db = 0; db < 4; db++) acc[db] = (f32x4){0.f, 0.f, 0.f, 0.f};
  accd = (f32x4){0.f, 0.f, 0.f, 0.f};

  char* wbase = (char*)whb4 + half * 16384;
  int ts = t & 255;
  int r_ = ts >> 2, ch_ = ts & 3;
  int jtbase = half * 16;
  const char* gbase = (const char*)(wht + (size_t)(bh * 64 + r_) * 2048) + jtbase * 128;
  int sw = (r_ & 7) << 4;
  u32x4 R0, R1;

#define LOADT(jt_) { const u32x4* gp = (const u32x4*)(gbase + (jt_) * 128 + ch_ * 32); \
                     R0 = gp[0]; R1 = gp[1]; }
#define WRITET(pb_) { char* wb_ = (pb_); \
                      *(u32x4*)(wb_ + r_ * 128 + ((ch_ * 32) ^ sw)) = R0; \
                      *(u32x4*)(wb_ + r_ * 128 + ((ch_ * 32 + 16) ^ sw)) = R1; }

  LOADT(0); WRITET(wbase); LOADT(1);

  for (int jt = 0; jt < 16; jt++) {
    int cur = jt & 1;
    __syncthreads();                      // drains prefetch vmem + dbuf writes
    if (jt < 15) WRITET(wbase + (cur ^ 1) * 8192);   // tile jt+1 -> other buf
    if (jt < 14) LOADT(jt + 2);                      // issue tile jt+2 loads
    const char* wbufc = wbase + cur * 8192;
    int jglob = jtbase + jt;

#pragma unroll
    for (int ks = 0; ks < 2; ks++) {
      unsigned adjw = adj_lds[(w * 16 + m) * 65 + jglob * 2 + ks];
      unsigned bits = (adjw >> (g * 8)) & 0xffu;
      const float* up = &ul[jglob * 64 + ks * 32 + g * 8];
      const float* vp = &vl[jglob * 64 + ks * 32 + g * 8];
      f32x4 u0 = *(const f32x4*)up, u1 = *(const f32x4*)(up + 4);
      f32x4 v0 = *(const f32x4*)vp, v1 = *(const f32x4*)(vp + 4);
      float pm[8];
#pragma unroll
      for (int e = 0; e < 8; e++) {
        float ue = (e < 4) ? u0[e] : u1[e - 4];
        float ve = (e < 4) ? v0[e] : v1[e - 4];
        float p = fmaxf(Af * ue, Bf * ve);            // leaky-exp, factorized
        unsigned keep = (unsigned)(((int)(bits << (31 - e))) >> 31);
        pm[e] = __builtin_bit_cast(float, __builtin_bit_cast(unsigned, p) & keep);
      }
      u32x4 afu;
#pragma unroll
      for (int e2 = 0; e2 < 4; e2++) {
        unsigned rr_;
        asm("v_cvt_pk_bf16_f32 %0, %1, %2" : "=v"(rr_) : "v"(pm[2 * e2]), "v"(pm[2 * e2 + 1]));
        afu[e2] = rr_;
      }
      s16x8 af = __builtin_bit_cast(s16x8, afu);
#pragma unroll
      for (int db = 0; db < 4; db++) {
        int dl = db * 16 + m;
        int off = dl * 128 + ((ks * 64 + g * 16) ^ ((dl & 7) << 4));
        s16x8 bf = *(const s16x8*)(wbufc + off);
        acc[db] = __builtin_amdgcn_mfma_f32_16x16x32_bf16(af, bf, acc[db], 0, 0, 0);
      }
      accd = __builtin_amdgcn_mfma_f32_16x16x32_bf16(af, bones, accd, 0, 0, 0);
    }
  }
#undef LOADT
#undef WRITET

  __syncthreads();                        // both halves done with adj_lds reads
  float* accl = (float*)adj_lds;          // reuse: [row][65] (col 64 = den)
  if (half == 1) {
#pragma unroll
    for (int db = 0; db < 4; db++)
#pragma unroll
      for (int r = 0; r < 4; r++)
        accl[(w * 16 + 4 * g + r) * 65 + db * 16 + m] = acc[db][r];
    if (m == 0) {
#pragma unroll
      for (int r = 0; r < 4; r++)
        accl[(w * 16 + 4 * g + r) * 65 + 64] = accd[r];
    }
  }
  __syncthreads();

  if (half == 0) {
#pragma unroll
    for (int db = 0; db < 4; db++)
#pragma unroll
      for (int r = 0; r < 4; r++)
        acc[db][r] += accl[(w * 16 + 4 * g + r) * 65 + db * 16 + m];
    float inv[4];
#pragma unroll
    for (int r = 0; r < 4; r++) {
      float dtot = accd[r] + accl[(w * 16 + 4 * g + r) * 65 + 64];
      inv[r] = dtot > 0.f ? 1.0f / dtot : 0.f;  // all-masked row -> zeros
    }

    float sums[4] = {0.f, 0.f, 0.f, 0.f}, sqs[4] = {0.f, 0.f, 0.f, 0.f};
#pragma unroll
    for (int r = 0; r < 4; r++) {
      int n = i0 + w * 16 + 4 * g + r;
#pragma unroll
      for (int db = 0; db < 4; db++) {
        float val = acc[db][r] * inv[r];
        hnew[(size_t)(b * 2048 + n) * 256 + hh * 64 + db * 16 + m] = val;
        sums[db] += val;
        sqs[db] += val * val;
      }
    }
#pragma unroll
    for (int db = 0; db < 4; db++) {
      sums[db] += __shfl_xor(sums[db], 16); sums[db] += __shfl_xor(sums[db], 32);
      sqs[db]  += __shfl_xor(sqs[db], 16);  sqs[db]  += __shfl_xor(sqs[db], 32);
    }
    if (g == 0) {
#pragma unroll
      for (int db = 0; db < 4; db++) {
        redS[w * 64 + db * 16 + m] = sums[db];
        redQ[w * 64 + db * 16 + m] = sqs[db];
      }
    }
  }
  __syncthreads();
  if (t < 64) {
    float ts2 = redS[t] + redS[64 + t] + redS[128 + t] + redS[192 + t];
    float tq = redQ[t] + redQ[64 + t] + redQ[128 + t] + redQ[192 + t];
    atomicAdd(&chsum[hh * 64 + t], ts2);
    atomicAdd(&chsq[hh * 64 + t], tq);
  }
}

// ---------------- Kernel D: BN(+stats inline) + ELU -----------------------
__global__ __launch_bounds__(256) void k_bn_elu(const float* __restrict__ hnew,
                                                const float* __restrict__ chsum,
                                                const float* __restrict__ chsq,
                                                const float* __restrict__ gamma,
                                                const float* __restrict__ beta,
                                                float* __restrict__ out) {
  int idx4 = blockIdx.x * 256 + threadIdx.x;
  f32x4 x = ((const f32x4*)hnew)[idx4];
  int c0 = (idx4 * 4) & 255;
  f32x4 s = *(const f32x4*)(chsum + c0);
  f32x4 sq = *(const f32x4*)(chsq + c0);
  f32x4 gm = *(const f32x4*)(gamma + c0);
  f32x4 bt = *(const f32x4*)(beta + c0);
  f32x4 y;
#pragma unroll
  for (int e = 0; e < 4; e++) {
    float mean = s[e] * (1.0f / 8192.0f);
    float var = sq[e] * (1.0f / 8192.0f) - mean * mean;
    float sc = gm[e] * rsqrtf(var + BNEPS);
    float v = (x[e] - mean) * sc + bt[e];
    y[e] = v > 0.f ? v : expm1f(v);
  }
  ((f32x4*)out)[idx4] = y;
}

extern "C" void kernel_launch(void* const* d_in, const int* in_sizes, int n_in,
                              void* d_out, int out_size, void* d_ws, size_t ws_size,
                              hipStream_t stream) {
  const float* h = (const float*)d_in[0];
  const float* W = (const float*)d_in[1];
  const float* a = (const float*)d_in[2];
  const float* gamma = (const float*)d_in[3];
  const float* beta = (const float*)d_in[4];
  const int* adj = (const int*)d_in[5];

  char* ws = (char*)d_ws;
  unsigned* adjb = (unsigned*)ws;                                  // 512 KB
  unsigned short* wht = (unsigned short*)(ws + (512 << 10));       // 4 MB
  float* src = (float*)(ws + (512 << 10) + (4 << 20));             // 128 KB
  float* dst = src + 16 * 2048;                                    // 128 KB
  float* chsum = dst + 16 * 2048;                                  // 256
  float* chsq = chsum + 256;                                       // 256
  float* hnew = (float*)(ws + (512 << 10) + (5 << 20));            // 8 MB

  k_pre<<<512 + (N_ * N_) / 256, 256, 0, stream>>>(adj, W, h, a, adjb, chsum,
                                                   wht, src, dst);
  k_attn<<<B_ * H_ * (N_ / 64), 512, 0, stream>>>(adjb, wht, src, dst,
                                                  hnew, chsum, chsq);
  k_bn_elu<<<(B_ * N_ * HD_) / 1024, 256, 0, stream>>>(hnew, chsum, chsq,
                                                       gamma, beta, (float*)d_out);
}